// Round 4
// baseline (1839.783 us; speedup 1.0000x reference)
//
#include <hip/hip_runtime.h>
#include <math.h>
#include <stdint.h>

// Problem: B=4, S=4096, D=2048, E=64, TOP_K=2
#define M_TOK  16384
#define D_DIM  2048
#define E_EXP  64
#define KCC    4
#define KCHUNK (D_DIM / KCC)      // 512
#define NCOL   128                // [route 64 | noise 64]
#define TAU    2e-3f              // flag threshold on top-3 gaps (error ~1e-4 -> 20x margin)

typedef __bf16 bf16x8 __attribute__((ext_vector_type(8)));
typedef float  f32x16 __attribute__((ext_vector_type(16)));

// ---- workspace layout (bytes) ----
#define OFF_CNT   0
#define OFF_LIST  1024
#define OFF_BH    (128*1024)                       // bf16 hi frags [D/8][128][8]
#define OFF_BL    (OFF_BH + (D_DIM/8)*NCOL*16)     // bf16 lo frags
#define OFF_SLAB  (2*1024*1024)                    // f32 partials [KCC][M][128]
#define SLAB_STRIDE ((size_t)M_TOK * NCOL)

// ---------------- stage 0: W -> B-fragment-ordered bf16 hi/lo ----------------
// frag row (kb, n) holds B[k=kb*8+j][n], j=0..7, as 8 bf16 (16B).
__global__ __launch_bounds__(256) void build_bfrag(const float* __restrict__ Wr,
                                                   const float* __restrict__ Wn,
                                                   char* __restrict__ ws) {
    const int id = blockIdx.x * 256 + threadIdx.x;   // 0..32767 = kb*128+n
    if (id == 0) *(int*)(ws + OFF_CNT) = 0;          // zero flag counter (ws is poisoned)
    const int kb = id >> 7;
    const int n  = id & 127;
    const float* src = (n < 64) ? (Wr + n) : (Wn + n - 64);
    uint32_t h[8], l[8];
    #pragma unroll
    for (int j = 0; j < 8; ++j) {
        const float w = src[(size_t)(kb * 8 + j) * E_EXP];
        const uint32_t u   = __float_as_uint(w);
        const uint32_t hif = u & 0xFFFF0000u;        // truncation split (exact residual)
        const float lo = w - __uint_as_float(hif);
        h[j] = u >> 16;
        l[j] = __float_as_uint(lo) >> 16;
    }
    uint32_t hp[4], lp[4];
    #pragma unroll
    for (int p = 0; p < 4; ++p) {
        hp[p] = h[2*p] | (h[2*p+1] << 16);           // element 2p low, 2p+1 high
        lp[p] = l[2*p] | (l[2*p+1] << 16);
    }
    *(uint4*)(ws + OFF_BH + (size_t)id * 16) = make_uint4(hp[0], hp[1], hp[2], hp[3]);
    *(uint4*)(ws + OFF_BL + (size_t)id * 16) = make_uint4(lp[0], lp[1], lp[2], lp[3]);
}

// ---------------- stage 1: bf16x2-split MFMA GEMM, f32 partials ----------------
// grid 512 = 128 token-tiles x 4 K-chunks. Block = 4 waves; wave w: tokens
// [tile*128 + w*32, +32) x all 128 cols (4 col-tiles of 32).
// MFMA 32x32x16_bf16 layouts (measured, learn_hip m74/m101):
//   A[m][k]: m = lane&31, k = (lane>>5)*8 + j   (j = vector element)
//   B[k][n]: n = lane&31, k = (lane>>5)*8 + j
//   C/D:     col = lane&31, row = (reg&3) + 8*(reg>>2) + 4*(lane>>5)
__global__ __launch_bounds__(256, 2) void gemm_fast(const float* __restrict__ A,
                                                    char* __restrict__ ws) {
    const int tile = blockIdx.x & 127;
    const int kc   = blockIdx.x >> 7;
    const int tid  = threadIdx.x;
    const int w    = tid >> 6;
    const int lane = tid & 63;
    const int half = lane >> 5;
    const int l32  = lane & 31;
    const int tokBase = tile * 128;
    const int k0      = kc * KCHUNK;

    const float* Ap = A + (size_t)(tokBase + w * 32 + l32) * D_DIM + k0 + half * 8;
    const char* BHb = ws + OFF_BH + (((size_t)(k0 >> 3) + half) * NCOL + l32) * 16;
    const char* BLb = ws + OFF_BL + (((size_t)(k0 >> 3) + half) * NCOL + l32) * 16;

    f32x16 acc[4];
    #pragma unroll
    for (int ct = 0; ct < 4; ++ct)
        #pragma unroll
        for (int i = 0; i < 16; ++i) acc[ct][i] = 0.f;

    float4 a4[2][2];
    bf16x8 bh[2][4], bl[2][4];
    a4[0][0] = *(const float4*)(Ap);
    a4[0][1] = *(const float4*)(Ap + 4);
    #pragma unroll
    for (int ct = 0; ct < 4; ++ct) {
        bh[0][ct] = *(const bf16x8*)(BHb + ct * 512);
        bl[0][ct] = *(const bf16x8*)(BLb + ct * 512);
    }

    #pragma unroll 2
    for (int s = 0; s < KCHUNK / 16; ++s) {          // 32 K16-steps
        const int cur = s & 1, nxt = cur ^ 1;
        if (s < KCHUNK / 16 - 1) {                   // prefetch next step
            const float* ap = Ap + (s + 1) * 16;
            a4[nxt][0] = *(const float4*)(ap);
            a4[nxt][1] = *(const float4*)(ap + 4);
            #pragma unroll
            for (int ct = 0; ct < 4; ++ct) {
                bh[nxt][ct] = *(const bf16x8*)(BHb + (size_t)(s + 1) * 4096 + ct * 512);
                bl[nxt][ct] = *(const bf16x8*)(BLb + (size_t)(s + 1) * 4096 + ct * 512);
            }
        }
        // split A: hi = trunc16(a), lo = trunc16(a - hi)  (a - hi exact in f32)
        union { uint32_t u[4]; bf16x8 v; } Ah, Al;
        const float* af = (const float*)&a4[cur][0];
        #pragma unroll
        for (int p = 0; p < 4; ++p) {
            const float x0 = af[2*p], x1 = af[2*p+1];
            const uint32_t u0 = __float_as_uint(x0), u1 = __float_as_uint(x1);
            const uint32_t h0 = u0 & 0xFFFF0000u,   h1 = u1 & 0xFFFF0000u;
            const float lo0 = x0 - __uint_as_float(h0);
            const float lo1 = x1 - __uint_as_float(h1);
            Ah.u[p] = (u0 >> 16) | h1;
            Al.u[p] = (__float_as_uint(lo0) >> 16) | (__float_as_uint(lo1) & 0xFFFF0000u);
        }
        #pragma unroll
        for (int ct = 0; ct < 4; ++ct) {
            acc[ct] = __builtin_amdgcn_mfma_f32_32x32x16_bf16(Ah.v, bh[cur][ct], acc[ct], 0, 0, 0);
            acc[ct] = __builtin_amdgcn_mfma_f32_32x32x16_bf16(Ah.v, bl[cur][ct], acc[ct], 0, 0, 0);
            acc[ct] = __builtin_amdgcn_mfma_f32_32x32x16_bf16(Al.v, bh[cur][ct], acc[ct], 0, 0, 0);
        }
    }

    float* slab = (float*)(ws + OFF_SLAB) + (size_t)kc * SLAB_STRIDE;
    #pragma unroll
    for (int ct = 0; ct < 4; ++ct) {
        const int col = ct * 32 + l32;
        #pragma unroll
        for (int r = 0; r < 16; ++r) {
            const int row = (r & 3) + 8 * (r >> 2) + 4 * half;
            slab[(size_t)(tokBase + w * 32 + row) * NCOL + col] = acc[ct][r];
        }
    }
}

// ---------------- stage 2: sum partials + fp32 softplus + top-3 + flag ----------------
__device__ __forceinline__ void ins3(float v, int i,
                                     float& v0, int& i0, float& v1, int& i1, float& v2, int& i2) {
    if (v > v0 || (v == v0 && i < i0))      { v2=v1; i2=i1; v1=v0; i1=i0; v0=v; i0=i; }
    else if (v > v1 || (v == v1 && i < i1)) { v2=v1; i2=i1; v1=v; i1=i; }
    else if (v > v2 || (v == v2 && i < i2)) { v2=v; i2=i; }
}

__global__ __launch_bounds__(256) void epilogue(char* __restrict__ ws,
                                                const float* __restrict__ br,
                                                const float* __restrict__ bn,
                                                const float* __restrict__ noise,
                                                float* __restrict__ probs,
                                                float* __restrict__ idx_out) {
    const int tid   = threadIdx.x;
    const int t_loc = tid >> 2;
    const int s     = tid & 3;                 // col quarter
    const int token = blockIdx.x * 64 + t_loc;
    const float* slab = (const float*)(ws + OFF_SLAB);

    float lr[16], ln[16];
    #pragma unroll
    for (int j = 0; j < 16; ++j) { lr[j] = 0.f; ln[j] = 0.f; }
    #pragma unroll
    for (int kcv = 0; kcv < KCC; ++kcv) {
        const float* q = slab + (size_t)kcv * SLAB_STRIDE + (size_t)token * NCOL + s * 16;
        #pragma unroll
        for (int c = 0; c < 4; ++c) {
            const float4 a = *(const float4*)(q + 4 * c);
            lr[4*c+0] += a.x; lr[4*c+1] += a.y; lr[4*c+2] += a.z; lr[4*c+3] += a.w;
            const float4 b = *(const float4*)(q + 64 + 4 * c);
            ln[4*c+0] += b.x; ln[4*c+1] += b.y; ln[4*c+2] += b.z; ln[4*c+3] += b.w;
        }
    }

    const float* nz = noise + (size_t)token * E_EXP + s * 16;
    float v0 = -INFINITY, v1 = -INFINITY, v2 = -INFINITY;
    int   i0 = 999, i1 = 999, i2 = 999;
    #pragma unroll
    for (int j = 0; j < 16; ++j) {
        const int e = s * 16 + j;
        const float lnn = ln[j] + bn[e];
        const float sp  = fmaxf(lnn, 0.f) + log1pf(expf(-fabsf(lnn)));
        const float v   = fmaf(nz[j], sp, lr[j] + br[e]);
        ins3(v, e, v0, i0, v1, i1, v2, i2);
    }
    #pragma unroll
    for (int m = 1; m < 4; m <<= 1) {          // merge across the 4 lanes of this token
        const float w0 = __shfl_xor(v0, m), w1 = __shfl_xor(v1, m), w2 = __shfl_xor(v2, m);
        const int   j0 = __shfl_xor(i0, m), j1 = __shfl_xor(i1, m), j2 = __shfl_xor(i2, m);
        ins3(w0, j0, v0, i0, v1, i1, v2, i2);
        ins3(w1, j1, v0, i0, v1, i1, v2, i2);
        ins3(w2, j2, v0, i0, v1, i1, v2, i2);
    }

    const float e1  = expf(v1 - v0);
    const float den = 1.f + e1;
    const float pp0 = 1.f / den, pp1 = e1 / den;
    float* pb = probs + (size_t)token * E_EXP + s * 16;
    #pragma unroll
    for (int c = 0; c < 4; ++c) {
        float4 o;
        const int e = s * 16 + 4 * c;
        o.x = (e+0 == i0) ? pp0 : ((e+0 == i1) ? pp1 : 0.f);
        o.y = (e+1 == i0) ? pp0 : ((e+1 == i1) ? pp1 : 0.f);
        o.z = (e+2 == i0) ? pp0 : ((e+2 == i1) ? pp1 : 0.f);
        o.w = (e+3 == i0) ? pp0 : ((e+3 == i1) ? pp1 : 0.f);
        *(float4*)(pb + 4 * c) = o;
    }
    if (s == 0) {
        *(float2*)(idx_out + (size_t)token * 2) = make_float2((float)i0, (float)i1);
        if ((v0 - v1 < TAU) || (v1 - v2 < TAU)) {      // ambiguous -> exact recheck
            const int pos = atomicAdd((int*)(ws + OFF_CNT), 1);
            ((int*)(ws + OFF_LIST))[pos] = token;
        }
    }
}

// ---------------- stage 3: exact f64 recheck of flagged tokens ----------------
__global__ __launch_bounds__(256) void recheck(const float* __restrict__ A,
                                               const float* __restrict__ Wr,
                                               const float* __restrict__ br,
                                               const float* __restrict__ Wn,
                                               const float* __restrict__ bn,
                                               const float* __restrict__ noise,
                                               float* __restrict__ probs,
                                               float* __restrict__ idx_out,
                                               char* __restrict__ ws) {
    __shared__ double red[256];
    int n = *(const int*)(ws + OFF_CNT);
    if (n > M_TOK) n = M_TOK;
    const int* list = (const int*)(ws + OFF_LIST);
    const int tid = threadIdx.x;
    const int e = tid & 63, m = (tid >> 6) & 1, h = tid >> 7;
    const float* W = m ? Wn : Wr;

    for (int li = blockIdx.x; li < n; li += gridDim.x) {
        const int token = list[li];
        const float* ar = A + (size_t)token * D_DIM + h * 1024;
        const float* wp = W + (size_t)h * 1024 * E_EXP + e;
        double p0 = 0.0, p1 = 0.0;
        for (int k = 0; k < 1024; k += 2) {
            p0 = fma((double)ar[k],     (double)wp[(size_t)k * E_EXP],       p0);
            p1 = fma((double)ar[k + 1], (double)wp[(size_t)(k + 1) * E_EXP], p1);
        }
        red[tid] = p0 + p1;
        __syncthreads();
        if (tid < 64) {
            const double lrv = red[tid] + red[tid + 128] + (double)br[e];
            const double lnv = red[tid + 64] + red[tid + 192] + (double)bn[e];
            const double sp  = fmax(lnv, 0.0) + log1p(exp(-fabs(lnv)));
            const double v   = fma((double)noise[(size_t)token * E_EXP + e], sp, lrv);
            double v0 = v, v1 = -INFINITY;
            int    i0 = e, i1 = 999;
            #pragma unroll
            for (int msk = 1; msk < 64; msk <<= 1) {
                const double w0 = __shfl_xor(v0, msk), w1 = __shfl_xor(v1, msk);
                const int    j0 = __shfl_xor(i0, msk), j1 = __shfl_xor(i1, msk);
                if ((v0 > w0) || (v0 == w0 && i0 < j0)) {
                    if (!((v1 > w0) || (v1 == w0 && i1 < j0))) { v1 = w0; i1 = j0; }
                } else {
                    if ((v0 > w1) || (v0 == w1 && i0 < j1)) { v1 = v0; i1 = i0; }
                    else                                    { v1 = w1; i1 = j1; }
                    v0 = w0; i0 = j0;
                }
            }
            const double e1  = exp(v1 - v0);
            const double den = 1.0 + e1;
            const float pp0 = (float)(1.0 / den), pp1 = (float)(e1 / den);
            probs[(size_t)token * E_EXP + tid] = (tid == i0) ? pp0 : ((tid == i1) ? pp1 : 0.f);
            if (tid == 0)
                *(float2*)(idx_out + (size_t)token * 2) = make_float2((float)i0, (float)i1);
        }
        __syncthreads();
    }
}

extern "C" void kernel_launch(void* const* d_in, const int* in_sizes, int n_in,
                              void* d_out, int out_size, void* d_ws, size_t ws_size,
                              hipStream_t stream) {
    (void)in_sizes; (void)n_in; (void)out_size; (void)ws_size;
    const float* A  = (const float*)d_in[0];
    const float* Wr = (const float*)d_in[1];
    const float* br = (const float*)d_in[2];
    const float* Wn = (const float*)d_in[3];
    const float* bn = (const float*)d_in[4];
    const float* nz = (const float*)d_in[5];

    float* probs = (float*)d_out;                    // [4,4096,64] f32
    float* idxo  = probs + (size_t)M_TOK * E_EXP;    // [4,4096,2] as f32
    char*  ws    = (char*)d_ws;                      // needs ~36 MB (have >=67 MB)

    build_bfrag<<<128, 256, 0, stream>>>(Wr, Wn, ws);
    gemm_fast<<<128 * KCC, 256, 0, stream>>>(A, ws);
    epilogue<<<M_TOK / 64, 256, 0, stream>>>(ws, br, bn, nz, probs, idxo);
    recheck<<<256, 256, 0, stream>>>(A, Wr, br, Wn, bn, nz, probs, idxo, ws);
}

// Round 5
// 1240.569 us; speedup vs baseline: 1.4830x; 1.4830x over previous
//
#include <hip/hip_runtime.h>
#include <math.h>
#include <stdint.h>

// Problem: B=4, S=4096, D=2048, E=64, TOP_K=2
#define M_TOK  16384
#define D_DIM  2048
#define E_EXP  64
#define KCC    4
#define KCHUNK (D_DIM / KCC)      // 512
#define NCOL   128                // [route 64 | noise 64]
#define TAU    2e-3f              // flag threshold on top-3 gaps (split error ~1e-4 -> wide margin)

typedef __bf16 bf16x8 __attribute__((ext_vector_type(8)));
typedef float  f32x16 __attribute__((ext_vector_type(16)));

// ---- workspace layout (bytes) ----
#define OFF_CNT   0
#define OFF_LIST  1024
#define OFF_BH    (128*1024)                       // bf16 hi frags [D/8][128][8]
#define OFF_BL    (OFF_BH + (D_DIM/8)*NCOL*16)     // bf16 lo frags
#define OFF_SLAB  (2*1024*1024)                    // f32 partials [KCC][M][128]
#define SLAB_STRIDE ((size_t)M_TOK * NCOL)

// ---------------- stage 0: W -> B-fragment-ordered bf16 hi/lo ----------------
// frag row (kb, n) holds B[k=kb*8+j][n], j=0..7, as 8 bf16 (16B).
__global__ __launch_bounds__(256) void build_bfrag(const float* __restrict__ Wr,
                                                   const float* __restrict__ Wn,
                                                   char* __restrict__ ws) {
    const int id = blockIdx.x * 256 + threadIdx.x;   // 0..32767 = kb*128+n
    if (id == 0) *(int*)(ws + OFF_CNT) = 0;          // zero flag counter (ws is poisoned)
    const int kb = id >> 7;
    const int n  = id & 127;
    const float* src = (n < 64) ? (Wr + n) : (Wn + n - 64);
    uint32_t h[8], l[8];
    #pragma unroll
    for (int j = 0; j < 8; ++j) {
        const float w = src[(size_t)(kb * 8 + j) * E_EXP];
        const uint32_t u   = __float_as_uint(w);
        const uint32_t hif = u & 0xFFFF0000u;        // truncation split (exact residual)
        const float lo = w - __uint_as_float(hif);
        h[j] = u >> 16;
        l[j] = __float_as_uint(lo) >> 16;
    }
    uint32_t hp[4], lp[4];
    #pragma unroll
    for (int p = 0; p < 4; ++p) {
        hp[p] = h[2*p] | (h[2*p+1] << 16);           // element 2p low, 2p+1 high
        lp[p] = l[2*p] | (l[2*p+1] << 16);
    }
    *(uint4*)(ws + OFF_BH + (size_t)id * 16) = make_uint4(hp[0], hp[1], hp[2], hp[3]);
    *(uint4*)(ws + OFF_BL + (size_t)id * 16) = make_uint4(lp[0], lp[1], lp[2], lp[3]);
}

// ---------------- stage 1: bf16x2-split MFMA GEMM, f32 partials ----------------
// grid 1024 = 256 token-tiles(64 tok) x 4 K-chunks. Block = 4 waves; wave w:
// tokens [tile*64 + (w>>1)*32, +32) x cols [(w&1)*64, +64) (2 col-tiles of 32).
// Waves sharing tokens dedup A loads in L1. Register budget ~100 VGPR -> no spill
// (round-4 lesson: 4 col-tiles/wave needed 164 live VGPRs, spilled at 124, 7x slowdown).
// MFMA 32x32x16_bf16 layouts (measured, learn_hip m74/m101):
//   A[m][k]: m = lane&31, k = (lane>>5)*8 + j   (j = vector element)
//   B[k][n]: n = lane&31, k = (lane>>5)*8 + j
//   C/D:     col = lane&31, row = (reg&3) + 8*(reg>>2) + 4*(lane>>5)
__global__ __launch_bounds__(256, 3) void gemm_fast(const float* __restrict__ A,
                                                    char* __restrict__ ws) {
    const int tile = blockIdx.x & 255;
    const int kc   = blockIdx.x >> 8;
    const int tid  = threadIdx.x;
    const int w    = tid >> 6;
    const int lane = tid & 63;
    const int half = lane >> 5;
    const int l32  = lane & 31;
    const int tg   = w >> 1;            // token group
    const int cg   = w & 1;             // col group (cols cg*64 .. +63)
    const int tokBase = tile * 64 + tg * 32;
    const int k0      = kc * KCHUNK;

    const float* Ap = A + (size_t)(tokBase + l32) * D_DIM + k0 + half * 8;
    const char* BHb = ws + OFF_BH + (((size_t)(k0 >> 3) + half) * NCOL + cg * 64 + l32) * 16;
    const char* BLb = ws + OFF_BL + (((size_t)(k0 >> 3) + half) * NCOL + cg * 64 + l32) * 16;

    f32x16 acc[2];
    #pragma unroll
    for (int ct = 0; ct < 2; ++ct)
        #pragma unroll
        for (int i = 0; i < 16; ++i) acc[ct][i] = 0.f;

    float4 a4[2][2];
    bf16x8 bh[2][2], bl[2][2];
    a4[0][0] = *(const float4*)(Ap);
    a4[0][1] = *(const float4*)(Ap + 4);
    #pragma unroll
    for (int ct = 0; ct < 2; ++ct) {
        bh[0][ct] = *(const bf16x8*)(BHb + ct * 512);
        bl[0][ct] = *(const bf16x8*)(BLb + ct * 512);
    }

    #pragma unroll 2
    for (int s = 0; s < KCHUNK / 16; ++s) {          // 32 K16-steps
        const int cur = s & 1, nxt = cur ^ 1;
        if (s < KCHUNK / 16 - 1) {                   // prefetch next step
            const float* ap = Ap + (s + 1) * 16;
            a4[nxt][0] = *(const float4*)(ap);
            a4[nxt][1] = *(const float4*)(ap + 4);
            #pragma unroll
            for (int ct = 0; ct < 2; ++ct) {
                bh[nxt][ct] = *(const bf16x8*)(BHb + (size_t)(s + 1) * 4096 + ct * 512);
                bl[nxt][ct] = *(const bf16x8*)(BLb + (size_t)(s + 1) * 4096 + ct * 512);
            }
        }
        // split A: hi = trunc16(a), lo = trunc16(a - hi)  (a - hi exact in f32)
        union { uint32_t u[4]; bf16x8 v; } Ah, Al;
        const float* af = (const float*)&a4[cur][0];
        #pragma unroll
        for (int p = 0; p < 4; ++p) {
            const float x0 = af[2*p], x1 = af[2*p+1];
            const uint32_t u0 = __float_as_uint(x0), u1 = __float_as_uint(x1);
            const uint32_t h0 = u0 & 0xFFFF0000u,   h1 = u1 & 0xFFFF0000u;
            const float lo0 = x0 - __uint_as_float(h0);
            const float lo1 = x1 - __uint_as_float(h1);
            Ah.u[p] = (u0 >> 16) | h1;
            Al.u[p] = (__float_as_uint(lo0) >> 16) | (__float_as_uint(lo1) & 0xFFFF0000u);
        }
        #pragma unroll
        for (int ct = 0; ct < 2; ++ct) {
            acc[ct] = __builtin_amdgcn_mfma_f32_32x32x16_bf16(Ah.v, bh[cur][ct], acc[ct], 0, 0, 0);
            acc[ct] = __builtin_amdgcn_mfma_f32_32x32x16_bf16(Ah.v, bl[cur][ct], acc[ct], 0, 0, 0);
            acc[ct] = __builtin_amdgcn_mfma_f32_32x32x16_bf16(Al.v, bh[cur][ct], acc[ct], 0, 0, 0);
        }
    }

    float* slab = (float*)(ws + OFF_SLAB) + (size_t)kc * SLAB_STRIDE;
    #pragma unroll
    for (int ct = 0; ct < 2; ++ct) {
        const int col = cg * 64 + ct * 32 + l32;
        #pragma unroll
        for (int r = 0; r < 16; ++r) {
            const int row = (r & 3) + 8 * (r >> 2) + 4 * half;
            slab[(size_t)(tokBase + row) * NCOL + col] = acc[ct][r];
        }
    }
}

// ---------------- stage 2: sum partials + fp32 softplus + top-3 + flag ----------------
__device__ __forceinline__ void ins3(float v, int i,
                                     float& v0, int& i0, float& v1, int& i1, float& v2, int& i2) {
    if (v > v0 || (v == v0 && i < i0))      { v2=v1; i2=i1; v1=v0; i1=i0; v0=v; i0=i; }
    else if (v > v1 || (v == v1 && i < i1)) { v2=v1; i2=i1; v1=v; i1=i; }
    else if (v > v2 || (v == v2 && i < i2)) { v2=v; i2=i; }
}

__global__ __launch_bounds__(256) void epilogue(char* __restrict__ ws,
                                                const float* __restrict__ br,
                                                const float* __restrict__ bn,
                                                const float* __restrict__ noise,
                                                float* __restrict__ probs,
                                                float* __restrict__ idx_out) {
    const int tid   = threadIdx.x;
    const int t_loc = tid >> 2;
    const int s     = tid & 3;                 // col quarter
    const int token = blockIdx.x * 64 + t_loc;
    const float* slab = (const float*)(ws + OFF_SLAB);

    float lr[16], ln[16];
    #pragma unroll
    for (int j = 0; j < 16; ++j) { lr[j] = 0.f; ln[j] = 0.f; }
    #pragma unroll
    for (int kcv = 0; kcv < KCC; ++kcv) {
        const float* q = slab + (size_t)kcv * SLAB_STRIDE + (size_t)token * NCOL + s * 16;
        #pragma unroll
        for (int c = 0; c < 4; ++c) {
            const float4 a = *(const float4*)(q + 4 * c);
            lr[4*c+0] += a.x; lr[4*c+1] += a.y; lr[4*c+2] += a.z; lr[4*c+3] += a.w;
            const float4 b = *(const float4*)(q + 64 + 4 * c);
            ln[4*c+0] += b.x; ln[4*c+1] += b.y; ln[4*c+2] += b.z; ln[4*c+3] += b.w;
        }
    }

    const float* nz = noise + (size_t)token * E_EXP + s * 16;
    float v0 = -INFINITY, v1 = -INFINITY, v2 = -INFINITY;
    int   i0 = 999, i1 = 999, i2 = 999;
    #pragma unroll
    for (int j = 0; j < 16; ++j) {
        const int e = s * 16 + j;
        const float lnn = ln[j] + bn[e];
        const float sp  = fmaxf(lnn, 0.f) + log1pf(expf(-fabsf(lnn)));
        const float v   = fmaf(nz[j], sp, lr[j] + br[e]);
        ins3(v, e, v0, i0, v1, i1, v2, i2);
    }
    #pragma unroll
    for (int m = 1; m < 4; m <<= 1) {          // merge across the 4 lanes of this token
        const float w0 = __shfl_xor(v0, m), w1 = __shfl_xor(v1, m), w2 = __shfl_xor(v2, m);
        const int   j0 = __shfl_xor(i0, m), j1 = __shfl_xor(i1, m), j2 = __shfl_xor(i2, m);
        ins3(w0, j0, v0, i0, v1, i1, v2, i2);
        ins3(w1, j1, v0, i0, v1, i1, v2, i2);
        ins3(w2, j2, v0, i0, v1, i1, v2, i2);
    }

    const float e1  = expf(v1 - v0);
    const float den = 1.f + e1;
    const float pp0 = 1.f / den, pp1 = e1 / den;
    float* pb = probs + (size_t)token * E_EXP + s * 16;
    #pragma unroll
    for (int c = 0; c < 4; ++c) {
        float4 o;
        const int e = s * 16 + 4 * c;
        o.x = (e+0 == i0) ? pp0 : ((e+0 == i1) ? pp1 : 0.f);
        o.y = (e+1 == i0) ? pp0 : ((e+1 == i1) ? pp1 : 0.f);
        o.z = (e+2 == i0) ? pp0 : ((e+2 == i1) ? pp1 : 0.f);
        o.w = (e+3 == i0) ? pp0 : ((e+3 == i1) ? pp1 : 0.f);
        *(float4*)(pb + 4 * c) = o;
    }
    if (s == 0) {
        *(float2*)(idx_out + (size_t)token * 2) = make_float2((float)i0, (float)i1);
        if ((v0 - v1 < TAU) || (v1 - v2 < TAU)) {      // ambiguous -> exact recheck
            const int pos = atomicAdd((int*)(ws + OFF_CNT), 1);
            ((int*)(ws + OFF_LIST))[pos] = token;
        }
    }
}

// ---------------- stage 3: exact f64 recheck of flagged tokens ----------------
__global__ __launch_bounds__(256) void recheck(const float* __restrict__ A,
                                               const float* __restrict__ Wr,
                                               const float* __restrict__ br,
                                               const float* __restrict__ Wn,
                                               const float* __restrict__ bn,
                                               const float* __restrict__ noise,
                                               float* __restrict__ probs,
                                               float* __restrict__ idx_out,
                                               char* __restrict__ ws) {
    __shared__ double red[256];
    int n = *(const int*)(ws + OFF_CNT);
    if (n > M_TOK) n = M_TOK;
    const int* list = (const int*)(ws + OFF_LIST);
    const int tid = threadIdx.x;
    const int e = tid & 63, m = (tid >> 6) & 1, h = tid >> 7;
    const float* W = m ? Wn : Wr;

    for (int li = blockIdx.x; li < n; li += gridDim.x) {
        const int token = list[li];
        const float* ar = A + (size_t)token * D_DIM + h * 1024;
        const float* wp = W + (size_t)h * 1024 * E_EXP + e;
        double p0 = 0.0, p1 = 0.0;
        for (int k = 0; k < 1024; k += 2) {
            p0 = fma((double)ar[k],     (double)wp[(size_t)k * E_EXP],       p0);
            p1 = fma((double)ar[k + 1], (double)wp[(size_t)(k + 1) * E_EXP], p1);
        }
        red[tid] = p0 + p1;
        __syncthreads();
        if (tid < 64) {
            const double lrv = red[tid] + red[tid + 128] + (double)br[e];
            const double lnv = red[tid + 64] + red[tid + 192] + (double)bn[e];
            const double sp  = fmax(lnv, 0.0) + log1p(exp(-fabs(lnv)));
            const double v   = fma((double)noise[(size_t)token * E_EXP + e], sp, lrv);
            double v0 = v, v1 = -INFINITY;
            int    i0 = e, i1 = 999;
            #pragma unroll
            for (int msk = 1; msk < 64; msk <<= 1) {
                const double w0 = __shfl_xor(v0, msk), w1 = __shfl_xor(v1, msk);
                const int    j0 = __shfl_xor(i0, msk), j1 = __shfl_xor(i1, msk);
                if ((v0 > w0) || (v0 == w0 && i0 < j0)) {
                    if (!((v1 > w0) || (v1 == w0 && i1 < j0))) { v1 = w0; i1 = j0; }
                } else {
                    if ((v0 > w1) || (v0 == w1 && i0 < j1)) { v1 = v0; i1 = i0; }
                    else                                    { v1 = w1; i1 = j1; }
                    v0 = w0; i0 = j0;
                }
            }
            const double e1  = exp(v1 - v0);
            const double den = 1.0 + e1;
            const float pp0 = (float)(1.0 / den), pp1 = (float)(e1 / den);
            probs[(size_t)token * E_EXP + tid] = (tid == i0) ? pp0 : ((tid == i1) ? pp1 : 0.f);
            if (tid == 0)
                *(float2*)(idx_out + (size_t)token * 2) = make_float2((float)i0, (float)i1);
        }
        __syncthreads();
    }
}

extern "C" void kernel_launch(void* const* d_in, const int* in_sizes, int n_in,
                              void* d_out, int out_size, void* d_ws, size_t ws_size,
                              hipStream_t stream) {
    (void)in_sizes; (void)n_in; (void)out_size; (void)ws_size;
    const float* A  = (const float*)d_in[0];
    const float* Wr = (const float*)d_in[1];
    const float* br = (const float*)d_in[2];
    const float* Wn = (const float*)d_in[3];
    const float* bn = (const float*)d_in[4];
    const float* nz = (const float*)d_in[5];

    float* probs = (float*)d_out;                    // [4,4096,64] f32
    float* idxo  = probs + (size_t)M_TOK * E_EXP;    // [4,4096,2] as f32
    char*  ws    = (char*)d_ws;                      // needs ~36 MB (have >=67 MB)

    build_bfrag<<<128, 256, 0, stream>>>(Wr, Wn, ws);
    gemm_fast<<<256 * KCC, 256, 0, stream>>>(A, ws);
    epilogue<<<M_TOK / 64, 256, 0, stream>>>(ws, br, bn, nz, probs, idxo);
    recheck<<<256, 256, 0, stream>>>(A, Wr, br, Wn, bn, nz, probs, idxo, ws);
}

// Round 7
// 385.196 us; speedup vs baseline: 4.7762x; 3.2206x over previous
//
#include <hip/hip_runtime.h>
#include <math.h>
#include <stdint.h>

// Problem: B=4, S=4096, D=2048, E=64, TOP_K=2
#define M_TOK  16384
#define D_DIM  2048
#define E_EXP  64
#define KCC    4
#define KCHUNK (D_DIM / KCC)      // 512
#define NCOL   128                // [route 64 | noise 64]
#define TAU    2e-3f              // flag threshold on top-3 gaps (fast-path error ~2e-5 -> 100x margin)

typedef __bf16    bf16x8 __attribute__((ext_vector_type(8)));
typedef float     f32x16 __attribute__((ext_vector_type(16)));
typedef uint32_t  u32x4  __attribute__((ext_vector_type(4)));

// ---- workspace layout (bytes): ONLY write-then-read-within-call data ----
#define OFF_BH    0                                // bf16 hi frags [D/8][128][8]
#define OFF_BL    (OFF_BH + (D_DIM/8)*NCOL*16)     // bf16 lo frags
#define OFF_SLAB  (2*1024*1024)                    // f32 partials [KCC][M][128]
#define SLAB_STRIDE ((size_t)M_TOK * NCOL)

// ---------------- stage 0: W -> B-fragment-ordered bf16 hi/lo ----------------
__global__ __launch_bounds__(256) void build_bfrag(const float* __restrict__ Wr,
                                                   const float* __restrict__ Wn,
                                                   char* __restrict__ ws) {
    const int id = blockIdx.x * 256 + threadIdx.x;   // 0..32767 = kb*128+n
    const int kb = id >> 7;
    const int n  = id & 127;
    const float* src = (n < 64) ? (Wr + n) : (Wn + n - 64);
    u32x4 hp, lp;
    #pragma unroll
    for (int p = 0; p < 4; ++p) {
        const float w0 = src[(size_t)(kb * 8 + 2*p)     * E_EXP];
        const float w1 = src[(size_t)(kb * 8 + 2*p + 1) * E_EXP];
        const uint32_t u0 = __float_as_uint(w0), u1 = __float_as_uint(w1);
        const uint32_t h0 = u0 & 0xFFFF0000u,    h1 = u1 & 0xFFFF0000u;
        const float lo0 = w0 - __uint_as_float(h0);
        const float lo1 = w1 - __uint_as_float(h1);
        hp[p] = (u0 >> 16) | h1;
        lp[p] = (__float_as_uint(lo0) >> 16) | (__float_as_uint(lo1) & 0xFFFF0000u);
    }
    *(u32x4*)(ws + OFF_BH + (size_t)id * 16) = hp;
    *(u32x4*)(ws + OFF_BL + (size_t)id * 16) = lp;
}

// ---------------- stage 1: bf16x2-split MFMA GEMM, f32 partials ----------------
// HOT-LOOP RULE (rounds 4+5 lesson): NO arrays/unions/variable-indexed aggregates.
// R4: 164 live VGPRs -> scratch spill @124. R5: a4[2][2] -> PromoteAlloca to LDS.
// Named scalars + __builtin_bit_cast only.
// MFMA 32x32x16_bf16 layouts (measured, learn_hip m74/m101):
//   A[m][k]: m=lane&31, k=(lane>>5)*8+j ; B[k][n]: n=lane&31, same k
//   C/D: col=lane&31, row=(reg&3)+8*(reg>>2)+4*(lane>>5)
__device__ __forceinline__ void split2(float x0, float x1, uint32_t& hp, uint32_t& lp) {
    const uint32_t u0 = __float_as_uint(x0), u1 = __float_as_uint(x1);
    const uint32_t h0 = u0 & 0xFFFF0000u,    h1 = u1 & 0xFFFF0000u;
    const float lo0 = x0 - __uint_as_float(h0);   // exact residual
    const float lo1 = x1 - __uint_as_float(h1);
    hp = (u0 >> 16) | h1;
    lp = (__float_as_uint(lo0) >> 16) | (__float_as_uint(lo1) & 0xFFFF0000u);
}

__global__ __launch_bounds__(256, 3) void gemm_fast(const float* __restrict__ A,
                                                    char* __restrict__ ws) {
    const int tile = blockIdx.x & 255;
    const int kc   = blockIdx.x >> 8;
    const int tid  = threadIdx.x;
    const int w    = tid >> 6;
    const int lane = tid & 63;
    const int half = lane >> 5;
    const int l32  = lane & 31;
    const int tg   = w >> 1;            // token group
    const int cg   = w & 1;             // col group (cols cg*64 .. +63)
    const int tokBase = tile * 64 + tg * 32;
    const int k0      = kc * KCHUNK;

    const float* Ap = A + (size_t)(tokBase + l32) * D_DIM + k0 + half * 8;
    const char* BHb = ws + OFF_BH + (((size_t)(k0 >> 3) + half) * NCOL + cg * 64 + l32) * 16;
    const char* BLb = ws + OFF_BL + (((size_t)(k0 >> 3) + half) * NCOL + cg * 64 + l32) * 16;

    f32x16 acc0, acc1;
    #pragma unroll
    for (int i = 0; i < 16; ++i) { acc0[i] = 0.f; acc1[i] = 0.f; }

    #pragma unroll 4
    for (int s = 0; s < KCHUNK / 16; ++s) {          // 32 K16-steps
        const float* ap = Ap + s * 16;
        const float4 a0 = *(const float4*)(ap);
        const float4 a1 = *(const float4*)(ap + 4);
        const char* bhp = BHb + (size_t)s * 4096;    // step advances kb by 2 -> 2*NCOL*16B
        const char* blp = BLb + (size_t)s * 4096;
        const bf16x8 b0h = *(const bf16x8*)(bhp);
        const bf16x8 b1h = *(const bf16x8*)(bhp + 512);
        const bf16x8 b0l = *(const bf16x8*)(blp);
        const bf16x8 b1l = *(const bf16x8*)(blp + 512);

        u32x4 ahu, alu;
        uint32_t h, l;
        split2(a0.x, a0.y, h, l); ahu[0] = h; alu[0] = l;
        split2(a0.z, a0.w, h, l); ahu[1] = h; alu[1] = l;
        split2(a1.x, a1.y, h, l); ahu[2] = h; alu[2] = l;
        split2(a1.z, a1.w, h, l); ahu[3] = h; alu[3] = l;
        const bf16x8 Ah = __builtin_bit_cast(bf16x8, ahu);
        const bf16x8 Al = __builtin_bit_cast(bf16x8, alu);

        acc0 = __builtin_amdgcn_mfma_f32_32x32x16_bf16(Ah, b0h, acc0, 0, 0, 0);
        acc0 = __builtin_amdgcn_mfma_f32_32x32x16_bf16(Ah, b0l, acc0, 0, 0, 0);
        acc0 = __builtin_amdgcn_mfma_f32_32x32x16_bf16(Al, b0h, acc0, 0, 0, 0);
        acc1 = __builtin_amdgcn_mfma_f32_32x32x16_bf16(Ah, b1h, acc1, 0, 0, 0);
        acc1 = __builtin_amdgcn_mfma_f32_32x32x16_bf16(Ah, b1l, acc1, 0, 0, 0);
        acc1 = __builtin_amdgcn_mfma_f32_32x32x16_bf16(Al, b1h, acc1, 0, 0, 0);
    }

    float* slab = (float*)(ws + OFF_SLAB) + (size_t)kc * SLAB_STRIDE;
    {
        const int col0 = cg * 64 + l32;
        #pragma unroll
        for (int r = 0; r < 16; ++r) {
            const int row = (r & 3) + 8 * (r >> 2) + 4 * half;
            slab[(size_t)(tokBase + row) * NCOL + col0] = acc0[r];
        }
        const int col1 = cg * 64 + 32 + l32;
        #pragma unroll
        for (int r = 0; r < 16; ++r) {
            const int row = (r & 3) + 8 * (r >> 2) + 4 * half;
            slab[(size_t)(tokBase + row) * NCOL + col1] = acc1[r];
        }
    }
}

// ---------------- stage 2: sum partials + fp32 top-3 + in-block f64 recheck ----------------
__device__ __forceinline__ void ins3(float v, int i,
                                     float& v0, int& i0, float& v1, int& i1, float& v2, int& i2) {
    if (v > v0 || (v == v0 && i < i0))      { v2=v1; i2=i1; v1=v0; i1=i0; v0=v; i0=i; }
    else if (v > v1 || (v == v1 && i < i1)) { v2=v1; i2=i1; v1=v; i1=i; }
    else if (v > v2 || (v == v2 && i < i2)) { v2=v; i2=i; }
}

__global__ __launch_bounds__(256) void epilogue(const char* __restrict__ ws,
                                                const float* __restrict__ A,
                                                const float* __restrict__ Wr,
                                                const float* __restrict__ Wn,
                                                const float* __restrict__ br,
                                                const float* __restrict__ bn,
                                                const float* __restrict__ noise,
                                                float* __restrict__ probs,
                                                float* __restrict__ idx_out) {
    __shared__ int    flagCnt;
    __shared__ int    flagList[64];
    __shared__ double red[256];

    const int tid   = threadIdx.x;
    const int t_loc = tid >> 2;
    const int s     = tid & 3;                 // col quarter
    const int token = blockIdx.x * 64 + t_loc;
    const float* slab = (const float*)(ws + OFF_SLAB);

    if (tid == 0) flagCnt = 0;
    __syncthreads();

    float lr[16], ln[16];
    #pragma unroll
    for (int j = 0; j < 16; ++j) { lr[j] = 0.f; ln[j] = 0.f; }
    #pragma unroll
    for (int kcv = 0; kcv < KCC; ++kcv) {
        const float* q = slab + (size_t)kcv * SLAB_STRIDE + (size_t)token * NCOL + s * 16;
        #pragma unroll
        for (int c = 0; c < 4; ++c) {
            const float4 a = *(const float4*)(q + 4 * c);
            lr[4*c+0] += a.x; lr[4*c+1] += a.y; lr[4*c+2] += a.z; lr[4*c+3] += a.w;
            const float4 b = *(const float4*)(q + 64 + 4 * c);
            ln[4*c+0] += b.x; ln[4*c+1] += b.y; ln[4*c+2] += b.z; ln[4*c+3] += b.w;
        }
    }

    const float* nz = noise + (size_t)token * E_EXP + s * 16;
    float v0 = -INFINITY, v1 = -INFINITY, v2 = -INFINITY;
    int   i0 = 999, i1 = 999, i2 = 999;
    #pragma unroll
    for (int j = 0; j < 16; ++j) {
        const int e = s * 16 + j;
        const float lnn = ln[j] + bn[e];
        const float sp  = fmaxf(lnn, 0.f) + log1pf(expf(-fabsf(lnn)));
        const float v   = fmaf(nz[j], sp, lr[j] + br[e]);
        ins3(v, e, v0, i0, v1, i1, v2, i2);
    }
    #pragma unroll
    for (int m = 1; m < 4; m <<= 1) {          // merge across the token's 4 lanes
        const float w0 = __shfl_xor(v0, m), w1 = __shfl_xor(v1, m), w2 = __shfl_xor(v2, m);
        const int   j0 = __shfl_xor(i0, m), j1 = __shfl_xor(i1, m), j2 = __shfl_xor(i2, m);
        ins3(w0, j0, v0, i0, v1, i1, v2, i2);
        ins3(w1, j1, v0, i0, v1, i1, v2, i2);
        ins3(w2, j2, v0, i0, v1, i1, v2, i2);
    }

    const float e1  = expf(v1 - v0);
    const float den = 1.f + e1;
    const float pp0 = 1.f / den, pp1 = e1 / den;
    float* pb = probs + (size_t)token * E_EXP + s * 16;
    #pragma unroll
    for (int c = 0; c < 4; ++c) {
        float4 o;
        const int e = s * 16 + 4 * c;
        o.x = (e+0 == i0) ? pp0 : ((e+0 == i1) ? pp1 : 0.f);
        o.y = (e+1 == i0) ? pp0 : ((e+1 == i1) ? pp1 : 0.f);
        o.z = (e+2 == i0) ? pp0 : ((e+2 == i1) ? pp1 : 0.f);
        o.w = (e+3 == i0) ? pp0 : ((e+3 == i1) ? pp1 : 0.f);
        *(float4*)(pb + 4 * c) = o;
    }
    if (s == 0) {
        *(float2*)(idx_out + (size_t)token * 2) = make_float2((float)i0, (float)i1);
        if ((v0 - v1 < TAU) || (v1 - v2 < TAU)) {      // ambiguous -> exact in-block recheck
            const int pos = atomicAdd(&flagCnt, 1);    // LDS atomic, block-local
            flagList[pos] = t_loc;
        }
    }
    __syncthreads();   // flags visible; also orders the fast-path probs/idx stores above
                       // (barrier drains vmcnt) before any recheck overwrite below

    // ---- exact f64 recheck of this block's flagged tokens (all 256 threads) ----
    const int nf = flagCnt;
    const int e  = tid & 63;
    const int m  = (tid >> 6) & 1;
    const int h  = tid >> 7;
    const float* W = m ? Wn : Wr;
    for (int f = 0; f < nf; ++f) {
        const int tok2 = blockIdx.x * 64 + flagList[f];
        const float* ar = A + (size_t)tok2 * D_DIM + h * 1024;
        const float* wp = W + (size_t)h * 1024 * E_EXP + e;
        double p0 = 0.0, p1 = 0.0;
        for (int k = 0; k < 1024; k += 2) {
            p0 = fma((double)ar[k],     (double)wp[(size_t)k * E_EXP],       p0);
            p1 = fma((double)ar[k + 1], (double)wp[(size_t)(k + 1) * E_EXP], p1);
        }
        red[tid] = p0 + p1;
        __syncthreads();
        if (tid < 64) {
            const double lrv = red[tid] + red[tid + 128] + (double)br[e];
            const double lnv = red[tid + 64] + red[tid + 192] + (double)bn[e];
            const double sp  = fmax(lnv, 0.0) + log1p(exp(-fabs(lnv)));
            const double v   = fma((double)noise[(size_t)tok2 * E_EXP + e], sp, lrv);
            double a0 = v, a1 = -INFINITY;
            int    j0 = e, j1 = 999;
            #pragma unroll
            for (int msk = 1; msk < 64; msk <<= 1) {
                const double w0 = __shfl_xor(a0, msk), w1 = __shfl_xor(a1, msk);
                const int    q0 = __shfl_xor(j0, msk), q1 = __shfl_xor(j1, msk);
                if ((a0 > w0) || (a0 == w0 && j0 < q0)) {
                    if (!((a1 > w0) || (a1 == w0 && j1 < q0))) { a1 = w0; j1 = q0; }
                } else {
                    if ((a0 > w1) || (a0 == w1 && j0 < q1)) { a1 = a0; j1 = j0; }
                    else                                    { a1 = w1; j1 = q1; }
                    a0 = w0; j0 = q0;
                }
            }
            const double ex  = exp(a1 - a0);
            const double dn  = 1.0 + ex;
            const float q0f = (float)(1.0 / dn), q1f = (float)(ex / dn);
            probs[(size_t)tok2 * E_EXP + tid] = (tid == j0) ? q0f : ((tid == j1) ? q1f : 0.f);
            if (tid == 0)
                *(float2*)(idx_out + (size_t)tok2 * 2) = make_float2((float)j0, (float)j1);
        }
        __syncthreads();
    }
}

extern "C" void kernel_launch(void* const* d_in, const int* in_sizes, int n_in,
                              void* d_out, int out_size, void* d_ws, size_t ws_size,
                              hipStream_t stream) {
    (void)in_sizes; (void)n_in; (void)out_size; (void)ws_size;
    const float* A  = (const float*)d_in[0];
    const float* Wr = (const float*)d_in[1];
    const float* br = (const float*)d_in[2];
    const float* Wn = (const float*)d_in[3];
    const float* bn = (const float*)d_in[4];
    const float* nz = (const float*)d_in[5];

    float* probs = (float*)d_out;                    // [4,4096,64] f32
    float* idxo  = probs + (size_t)M_TOK * E_EXP;    // [4,4096,2] as f32
    char*  ws    = (char*)d_ws;                      // ~34 MB used (have >=67 MB)

    build_bfrag<<<128, 256, 0, stream>>>(Wr, Wn, ws);
    gemm_fast<<<256 * KCC, 256, 0, stream>>>(A, ws);
    epilogue<<<M_TOK / 64, 256, 0, stream>>>(ws, A, Wr, Wn, br, bn, nz, probs, idxo);
}